// Round 3
// baseline (441.920 us; speedup 1.0000x reference)
//
#include <hip/hip_runtime.h>
#include <cfloat>
#include <stdint.h>

#define P_TOT     4194304      // 8*512*1024 pixels
#define HW_       524288       // 512*1024
#define NCLS      19
#define IGNORE_IDX 255
#define MIN_KEPT_ 100000
#define THR       0.7f
#define L2E       1.44269504088896340736f
#define LN2       0.69314718055994530942f

#define NWAVE          1024    // pass1: 1024 single-wave blocks (4/CU, LDS-limited)
#define TILES_PER_WAVE 16      // 1024 waves * 16 tiles * 256 px = P_TOT
#define TILE_PX        256     // pixels per tile (64 lanes * 4 px)
#define BUF_BYTES      20480   // (19 planes + target) * 1024 B
// LDS per block: 2 * BUF_BYTES = 40960 B -> exactly 4 blocks/CU of 160 KiB

// async global->LDS DMA, 16 B/lane; LDS dest = wave-uniform base + lane*16
__device__ __forceinline__ void dma16(const void* g, void* l){
  __builtin_amdgcn_global_load_lds(
      (const __attribute__((address_space(1))) uint32_t*)g,
      (__attribute__((address_space(3))) uint32_t*)l, 16, 0, 0);
}

__device__ __forceinline__ double wred_d(double v){
  #pragma unroll
  for (int o = 32; o > 0; o >>= 1) v += __shfl_down(v, o, 64);
  return v;
}
__device__ __forceinline__ unsigned wred_u(unsigned v){
  #pragma unroll
  for (int o = 32; o > 0; o >>= 1) v += __shfl_down(v, o, 64);
  return v;
}

// Pass 1: persistent single-wave blocks, double-buffered async LDS staging.
// Each wave DMAs (19 planes + target) x 1 KB per tile and consumes ONLY its
// own chunks -> no __syncthreads anywhere (avoids barrier vmcnt(0) drain).
// Explicit s_waitcnt vmcnt(20) lets tile t+1's 20 DMA loads stay in flight
// while tile t is computed.
__global__ __launch_bounds__(64) void ohem_pass1(
    const float* __restrict__ logits, const int* __restrict__ tgt,
    double* __restrict__ p_sle, double* __restrict__ p_sva,
    unsigned* __restrict__ p_cnt)
{
  __shared__ uint8_t lds[2 * BUF_BYTES];
  const int lane = threadIdx.x;            // 0..63
  const int t0   = blockIdx.x * TILES_PER_WAVE;

  { // prologue: issue DMA for tile 0 into buffer 0
    int p0 = t0 * TILE_PX;
    int n = p0 >> 19, r0 = p0 & (HW_ - 1);
    const float* pb = logits + (size_t)n * (NCLS * (size_t)HW_) + r0 + lane * 4;
    #pragma unroll
    for (int c = 0; c < NCLS; c++)
      dma16(pb + (size_t)c * HW_, &lds[c * 1024]);
    dma16(tgt + p0 + lane * 4, &lds[19 * 1024]);
  }

  double sle = 0.0, sva = 0.0;
  unsigned cnt = 0;                         // low16 = num_valid, high16 = count(pred<=THR)

  for (int i = 0; i < TILES_PER_WAVE; i++){
    const uint8_t* buf = &lds[(i & 1) * BUF_BYTES];

    if (i + 1 < TILES_PER_WAVE){            // issue DMA for tile i+1, other buffer
      int p0 = (t0 + i + 1) * TILE_PX;
      int n = p0 >> 19, r0 = p0 & (HW_ - 1);
      const float* pb = logits + (size_t)n * (NCLS * (size_t)HW_) + r0 + lane * 4;
      uint8_t* nbuf = &lds[((i + 1) & 1) * BUF_BYTES];
      #pragma unroll
      for (int c = 0; c < NCLS; c++)
        dma16(pb + (size_t)c * HW_, nbuf + c * 1024);
      dma16(tgt + p0 + lane * 4, nbuf + 19 * 1024);
      __builtin_amdgcn_s_waitcnt(0x4F74);   // vmcnt(20): tile i landed, i+1 in flight
    } else {
      __builtin_amdgcn_s_waitcnt(0x0F70);   // vmcnt(0): last tile landed
    }

    // ---- compute tile i (4 px per lane, from own LDS chunk) ----
    int4 tl = *((const int4*)(buf + 19 * 1024) + lane);

    float4 vals[NCLS];
    float4 mx; mx.x = mx.y = mx.z = mx.w = -FLT_MAX;
    #pragma unroll
    for (int c = 0; c < NCLS; c++){
      float4 v = *((const float4*)(buf + c * 1024) + lane);
      vals[c] = v;
      mx.x = fmaxf(mx.x, v.x); mx.y = fmaxf(mx.y, v.y);
      mx.z = fmaxf(mx.z, v.z); mx.w = fmaxf(mx.w, v.w);
    }
    float4 nm;
    nm.x = -mx.x * L2E; nm.y = -mx.y * L2E;
    nm.z = -mx.z * L2E; nm.w = -mx.w * L2E;
    float4 se; se.x = se.y = se.z = se.w = 0.f;
    #pragma unroll
    for (int c = 0; c < NCLS; c++){
      se.x += __builtin_amdgcn_exp2f(fmaf(vals[c].x, L2E, nm.x));
      se.y += __builtin_amdgcn_exp2f(fmaf(vals[c].y, L2E, nm.y));
      se.z += __builtin_amdgcn_exp2f(fmaf(vals[c].z, L2E, nm.z));
      se.w += __builtin_amdgcn_exp2f(fmaf(vals[c].w, L2E, nm.w));
    }

    int q0 = (tl.x != IGNORE_IDX), q1 = (tl.y != IGNORE_IDX);
    int q2 = (tl.z != IGNORE_IDX), q3 = (tl.w != IGNORE_IDX);
    int l0 = q0 ? tl.x : 0, l1 = q1 ? tl.y : 0;
    int l2 = q2 ? tl.z : 0, l3 = q3 ? tl.w : 0;
    // label logit gather from LDS (bank conflicts <=8-way on 4 reads: negligible)
    float g0 = *(const float*)(buf + l0 * 1024 + lane * 16 + 0);
    float g1 = *(const float*)(buf + l1 * 1024 + lane * 16 + 4);
    float g2 = *(const float*)(buf + l2 * 1024 + lane * 16 + 8);
    float g3 = *(const float*)(buf + l3 * 1024 + lane * 16 + 12);

    float lp0 = (g0 - mx.x) - __builtin_amdgcn_logf(se.x) * LN2;
    float lp1 = (g1 - mx.y) - __builtin_amdgcn_logf(se.y) * LN2;
    float lp2 = (g2 - mx.z) - __builtin_amdgcn_logf(se.z) * LN2;
    float lp3 = (g3 - mx.w) - __builtin_amdgcn_logf(se.w) * LN2;
    float pd0 = __builtin_amdgcn_exp2f(lp0 * L2E);
    float pd1 = __builtin_amdgcn_exp2f(lp1 * L2E);
    float pd2 = __builtin_amdgcn_exp2f(lp2 * L2E);
    float pd3 = __builtin_amdgcn_exp2f(lp3 * L2E);

    #define PIXEL(Q, LP, PD) {                                   \
      if (Q){                                                    \
        cnt += 1u; sva += (double)(LP);                          \
        if ((PD) <= THR){ cnt += 1u << 16; sle += (double)(LP); }\
      }                                                          \
    }
    PIXEL(q0, lp0, pd0) PIXEL(q1, lp1, pd1)
    PIXEL(q2, lp2, pd2) PIXEL(q3, lp3, pd3)
    #undef PIXEL
  }

  sle = wred_d(sle); sva = wred_d(sva); cnt = wred_u(cnt);
  if (lane == 0){
    p_sle[blockIdx.x] = sle;
    p_sva[blockIdx.x] = sva;
    p_cnt[blockIdx.x] = cnt;
  }
}

// Finish: reduce partials, resolve the three OHEM cases.
// Cold fallback (exact bitwise radix-select of the kth-smallest pred) only
// runs when count(valid & pred<=0.7) < MIN_KEPT < num_valid — never for the
// bench distribution, but kept for full correctness.
__global__ __launch_bounds__(1024) void ohem_finish(
    const float* __restrict__ logits, const int* __restrict__ tgt,
    const double* __restrict__ p_sle, const double* __restrict__ p_sva,
    const unsigned* __restrict__ p_cnt,
    unsigned* __restrict__ keys, float* __restrict__ logp,
    float* __restrict__ out)
{
  __shared__ double  rs1[16], rs2[16];
  __shared__ unsigned rc1[16], rc2[16];
  __shared__ unsigned s_flag, s_prefix, s_rank;
  __shared__ unsigned s_hist[4096];

  int t = threadIdx.x;
  double sle = p_sle[t], sva = p_sva[t];
  unsigned c0 = p_cnt[t];
  unsigned cva = c0 & 0xFFFFu, cle = c0 >> 16;

  sle = wred_d(sle); sva = wred_d(sva);
  cle = wred_u(cle); cva = wred_u(cva);
  int wv = t >> 6, ln = t & 63;
  if (ln == 0){ rs1[wv] = sle; rs2[wv] = sva; rc1[wv] = cle; rc2[wv] = cva; }
  __syncthreads();
  if (t == 0){
    double S1 = 0, S2 = 0; unsigned C1 = 0, C2 = 0;
    for (int i = 0; i < 16; i++){ S1 += rs1[i]; S2 += rs2[i]; C1 += rc1[i]; C2 += rc2[i]; }
    unsigned flag;
    if (C2 <= MIN_KEPT_){                       // do_ohem false: keep all valid
      unsigned d = C2 > 1u ? C2 : 1u;
      out[0] = (float)(-S2 / (double)d);
      flag = 0;
    } else if (C1 >= MIN_KEPT_){                // kth <= 0.7 => threshold = 0.7
      out[0] = (float)(-S1 / (double)C1);
      flag = 0;
    } else flag = 1;                            // need exact kth (> 0.7)
    s_flag = flag;
  }
  __syncthreads();
  if (!s_flag) return;

  // ---------- cold fallback: exact selection ----------
  for (int p = t; p < P_TOT; p += 1024){
    int n = p >> 19; int r = p & (HW_ - 1);
    const float* bp = logits + (size_t)n * (NCLS * (size_t)HW_) + r;
    int lab = tgt[p];
    int lv  = (lab != IGNORE_IDX);
    int ls  = lv ? lab : 0;
    float mxv = -FLT_MAX, va[NCLS];
    #pragma unroll
    for (int c = 0; c < NCLS; c++){
      float x = bp[(size_t)c * HW_];
      va[c] = x; mxv = fmaxf(mxv, x);
    }
    float xlv = va[0];
    #pragma unroll
    for (int c = 1; c < NCLS; c++) if (c == ls) xlv = va[c];
    float sev = 0.f;
    #pragma unroll
    for (int c = 0; c < NCLS; c++) sev += __expf(va[c] - mxv);
    float lp = (xlv - mxv) - __logf(sev);
    float pd = __expf(lp);
    keys[p] = lv ? __float_as_uint(pd) : 0xFFFFFFFFu;
    logp[p] = lp;
  }
  __syncthreads();

  unsigned prefix = 0, rank = MIN_KEPT_;        // 1-indexed rank
  #pragma unroll
  for (int rd = 0; rd < 3; rd++){
    const int sh = (rd == 0) ? 20 : (rd == 1) ? 8 : 0;
    const int nb = (rd == 2) ? 8 : 12;
    const unsigned nbin = 1u << nb;
    for (unsigned i = t; i < nbin; i += 1024) s_hist[i] = 0;
    __syncthreads();
    for (int p = t; p < P_TOT; p += 1024){
      unsigned k = keys[p];
      unsigned hi = (rd == 0) ? 0u : (k >> (sh + nb));
      if (hi == prefix) atomicAdd(&s_hist[(k >> sh) & (nbin - 1)], 1u);
    }
    __syncthreads();
    if (t == 0){
      unsigned cum = 0, b = 0;
      for (; b < nbin - 1; b++){
        unsigned cc = s_hist[b];
        if (cum + cc >= rank) break;
        cum += cc;
      }
      s_prefix = (prefix << nb) | b;
      s_rank = rank - cum;
    }
    __syncthreads();
    prefix = s_prefix; rank = s_rank;
    __syncthreads();
  }
  unsigned kb = prefix;                         // bit pattern of kth-smallest pred

  double s = 0.0; unsigned c = 0;
  for (int p = t; p < P_TOT; p += 1024){
    unsigned k = keys[p];
    if (k <= kb){ c++; s += (double)logp[p]; }  // invalid keys (0xFFFFFFFF) excluded
  }
  s = wred_d(s); c = wred_u(c);
  if (ln == 0){ rs1[wv] = s; rc1[wv] = c; }
  __syncthreads();
  if (t == 0){
    double S = 0; unsigned CC = 0;
    for (int i = 0; i < 16; i++){ S += rs1[i]; CC += rc1[i]; }
    unsigned d = CC > 1u ? CC : 1u;
    out[0] = (float)(-S / (double)d);
  }
}

extern "C" void kernel_launch(void* const* d_in, const int* in_sizes, int n_in,
                              void* d_out, int out_size, void* d_ws, size_t ws_size,
                              hipStream_t stream)
{
  const float* logits = (const float*)d_in[0];
  const int*   tgt    = (const int*)d_in[1];
  float* out = (float*)d_out;

  // ws layout: partial sums (hot path) then fallback arrays (cold only)
  double*   p_sle = (double*)d_ws;
  double*   p_sva = p_sle + NWAVE;
  unsigned* p_cnt = (unsigned*)(p_sva + NWAVE);
  unsigned* keys  = p_cnt + NWAVE;           // P_TOT uints (cold path only)
  float*    logp  = (float*)(keys + P_TOT);  // P_TOT floats (cold path only)

  hipLaunchKernelGGL(ohem_pass1, dim3(NWAVE), dim3(64), 0, stream,
                     logits, tgt, p_sle, p_sva, p_cnt);
  hipLaunchKernelGGL(ohem_finish, dim3(1), dim3(1024), 0, stream,
                     logits, tgt, p_sle, p_sva, p_cnt, keys, logp, out);
}

// Round 4
// 423.094 us; speedup vs baseline: 1.0445x; 1.0445x over previous
//
#include <hip/hip_runtime.h>
#include <cfloat>
#include <stdint.h>

#define P_TOT     4194304      // 8*512*1024 pixels
#define HW_       524288       // 512*1024
#define NCLS      19
#define IGNORE_IDX 255
#define MIN_KEPT_ 100000
#define THR       0.7f
#define L2E       1.44269504088896340736f
#define LN2       0.69314718055994530942f

#define SEG_PX    8192         // pixels per block
#define NSEG      512          // 512 * 8192 = P_TOT

__device__ __forceinline__ double wred_d(double v){
  #pragma unroll
  for (int o = 32; o > 0; o >>= 1) v += __shfl_down(v, o, 64);
  return v;
}
__device__ __forceinline__ unsigned wred_u(unsigned v){
  #pragma unroll
  for (int o = 32; o > 0; o >>= 1) v += __shfl_down(v, o, 64);
  return v;
}

// Pass 1: class-OUTER sweep with online-softmax state in registers.
// Each block owns 8192 contiguous pixels; per class step it reads a single
// 32 KB LINEAR run per plane (vs 1-4 KB chunks in R1-R3, which capped HBM at
// ~2.6 TB/s from DRAM row-buffer thrashing across ~20k tiny strided streams).
// State per thread: 16 px of (m, s, g) + labels; no LDS, no barriers.
__global__ __launch_bounds__(512) void ohem_pass1(
    const float* __restrict__ logits, const int* __restrict__ tgt,
    double* __restrict__ p_sle, double* __restrict__ p_sva,
    unsigned* __restrict__ p_cnt)
{
  const int t   = threadIdx.x;
  const int seg = blockIdx.x * SEG_PX;       // segment never crosses an image
  const int n   = seg >> 19;
  const int r0  = seg & (HW_ - 1);
  const float* plane0 = logits + (size_t)n * (NCLS * (size_t)HW_) + r0;

  int   lab[16];
  float m[16], s[16], g[16];

  #pragma unroll
  for (int j = 0; j < 4; j++){
    int4 tl = *(const int4*)(tgt + seg + j * 2048 + t * 4);
    lab[4*j+0] = tl.x; lab[4*j+1] = tl.y; lab[4*j+2] = tl.z; lab[4*j+3] = tl.w;
  }

  // class 0 initializes the online state
  #pragma unroll
  for (int j = 0; j < 4; j++){
    float4 v = *(const float4*)(plane0 + j * 2048 + t * 4);
    float vv[4] = {v.x, v.y, v.z, v.w};
    #pragma unroll
    for (int k = 0; k < 4; k++){
      int p = 4*j + k;
      m[p] = vv[k]; s[p] = 1.0f;
      g[p] = (lab[p] == 0) ? vv[k] : 0.0f;
    }
  }

  // classes 1..18 as 9 pairs: one rescale exp per 2 classes
  #pragma unroll 1
  for (int c = 1; c < NCLS; c += 2){
    const float* pA = plane0 + (size_t)c * HW_;
    const float* pB = pA + HW_;
    float4 va[4], vb[4];
    #pragma unroll
    for (int j = 0; j < 4; j++){
      va[j] = *(const float4*)(pA + j * 2048 + t * 4);
      vb[j] = *(const float4*)(pB + j * 2048 + t * 4);
    }
    #pragma unroll
    for (int j = 0; j < 4; j++){
      float xa[4] = {va[j].x, va[j].y, va[j].z, va[j].w};
      float xb[4] = {vb[j].x, vb[j].y, vb[j].z, vb[j].w};
      #pragma unroll
      for (int k = 0; k < 4; k++){
        int p = 4*j + k;
        float x = xa[k], y = xb[k];
        float mo = m[p];
        float mn = fmaxf(mo, fmaxf(x, y));
        float tt = mn * L2E;
        s[p] = s[p] * __builtin_amdgcn_exp2f(fmaf(mo, L2E, -tt))
             + __builtin_amdgcn_exp2f(fmaf(x, L2E, -tt))
             + __builtin_amdgcn_exp2f(fmaf(y, L2E, -tt));
        m[p] = mn;
        g[p] = (lab[p] == c)     ? x : g[p];
        g[p] = (lab[p] == c + 1) ? y : g[p];
      }
    }
  }

  double sle = 0.0, sva = 0.0; unsigned cnt = 0;  // lo16=valid, hi16=pred<=THR
  #pragma unroll
  for (int p = 0; p < 16; p++){
    float lp = (g[p] - m[p]) - __builtin_amdgcn_logf(s[p]) * LN2;
    float pd = __builtin_amdgcn_exp2f(lp * L2E);
    if (lab[p] != IGNORE_IDX){
      cnt += 1u; sva += (double)lp;
      if (pd <= THR){ cnt += 1u << 16; sle += (double)lp; }
    }
  }
  sle = wred_d(sle); sva = wred_d(sva); cnt = wred_u(cnt);

  __shared__ double  ld1[8], ld2[8];
  __shared__ unsigned lc[8];
  int wv = t >> 6, ln = t & 63;
  if (ln == 0){ ld1[wv] = sle; ld2[wv] = sva; lc[wv] = cnt; }
  __syncthreads();
  if (t == 0){
    double a = 0, b = 0; unsigned c2 = 0;
    for (int i = 0; i < 8; i++){ a += ld1[i]; b += ld2[i]; c2 += lc[i]; }
    p_sle[blockIdx.x] = a; p_sva[blockIdx.x] = b; p_cnt[blockIdx.x] = c2;
  }
}

// Finish: reduce partials, resolve the three OHEM cases.
// Cold fallback (exact bitwise radix-select of the kth-smallest pred) only
// runs when count(valid & pred<=0.7) < MIN_KEPT < num_valid — never for the
// bench distribution, but kept for full correctness.
__global__ __launch_bounds__(1024) void ohem_finish(
    const float* __restrict__ logits, const int* __restrict__ tgt,
    const double* __restrict__ p_sle, const double* __restrict__ p_sva,
    const unsigned* __restrict__ p_cnt,
    unsigned* __restrict__ keys, float* __restrict__ logp,
    float* __restrict__ out)
{
  __shared__ double  rs1[16], rs2[16];
  __shared__ unsigned rc1[16], rc2[16];
  __shared__ unsigned s_flag, s_prefix, s_rank;
  __shared__ unsigned s_hist[4096];

  int t = threadIdx.x;
  double sle = 0.0, sva = 0.0; unsigned cle = 0, cva = 0;
  for (int i = t; i < NSEG; i += 1024){
    sle += p_sle[i]; sva += p_sva[i];
    unsigned c = p_cnt[i];
    cva += c & 0xFFFFu; cle += c >> 16;
  }
  sle = wred_d(sle); sva = wred_d(sva);
  cle = wred_u(cle); cva = wred_u(cva);
  int wv = t >> 6, ln = t & 63;
  if (ln == 0){ rs1[wv] = sle; rs2[wv] = sva; rc1[wv] = cle; rc2[wv] = cva; }
  __syncthreads();
  if (t == 0){
    double S1 = 0, S2 = 0; unsigned C1 = 0, C2 = 0;
    for (int i = 0; i < 16; i++){ S1 += rs1[i]; S2 += rs2[i]; C1 += rc1[i]; C2 += rc2[i]; }
    unsigned flag;
    if (C2 <= MIN_KEPT_){                       // do_ohem false: keep all valid
      unsigned d = C2 > 1u ? C2 : 1u;
      out[0] = (float)(-S2 / (double)d);
      flag = 0;
    } else if (C1 >= MIN_KEPT_){                // kth <= 0.7 => threshold = 0.7
      out[0] = (float)(-S1 / (double)C1);
      flag = 0;
    } else flag = 1;                            // need exact kth (> 0.7)
    s_flag = flag;
  }
  __syncthreads();
  if (!s_flag) return;

  // ---------- cold fallback: exact selection ----------
  for (int p = t; p < P_TOT; p += 1024){
    int n = p >> 19; int r = p & (HW_ - 1);
    const float* bp = logits + (size_t)n * (NCLS * (size_t)HW_) + r;
    int lab = tgt[p];
    int lv  = (lab != IGNORE_IDX);
    int ls  = lv ? lab : 0;
    float mxv = -FLT_MAX, va[NCLS];
    #pragma unroll
    for (int c = 0; c < NCLS; c++){
      float x = bp[(size_t)c * HW_];
      va[c] = x; mxv = fmaxf(mxv, x);
    }
    float xlv = va[0];
    #pragma unroll
    for (int c = 1; c < NCLS; c++) if (c == ls) xlv = va[c];
    float sev = 0.f;
    #pragma unroll
    for (int c = 0; c < NCLS; c++) sev += __expf(va[c] - mxv);
    float lp = (xlv - mxv) - __logf(sev);
    float pd = __expf(lp);
    keys[p] = lv ? __float_as_uint(pd) : 0xFFFFFFFFu;
    logp[p] = lp;
  }
  __syncthreads();

  unsigned prefix = 0, rank = MIN_KEPT_;        // 1-indexed rank
  #pragma unroll
  for (int rd = 0; rd < 3; rd++){
    const int sh = (rd == 0) ? 20 : (rd == 1) ? 8 : 0;
    const int nb = (rd == 2) ? 8 : 12;
    const unsigned nbin = 1u << nb;
    for (unsigned i = t; i < nbin; i += 1024) s_hist[i] = 0;
    __syncthreads();
    for (int p = t; p < P_TOT; p += 1024){
      unsigned k = keys[p];
      unsigned hi = (rd == 0) ? 0u : (k >> (sh + nb));
      if (hi == prefix) atomicAdd(&s_hist[(k >> sh) & (nbin - 1)], 1u);
    }
    __syncthreads();
    if (t == 0){
      unsigned cum = 0, b = 0;
      for (; b < nbin - 1; b++){
        unsigned cc = s_hist[b];
        if (cum + cc >= rank) break;
        cum += cc;
      }
      s_prefix = (prefix << nb) | b;
      s_rank = rank - cum;
    }
    __syncthreads();
    prefix = s_prefix; rank = s_rank;
    __syncthreads();
  }
  unsigned kb = prefix;                         // bit pattern of kth-smallest pred

  double s = 0.0; unsigned c = 0;
  for (int p = t; p < P_TOT; p += 1024){
    unsigned k = keys[p];
    if (k <= kb){ c++; s += (double)logp[p]; }  // invalid keys (0xFFFFFFFF) excluded
  }
  s = wred_d(s); c = wred_u(c);
  if (ln == 0){ rs1[wv] = s; rc1[wv] = c; }
  __syncthreads();
  if (t == 0){
    double S = 0; unsigned CC = 0;
    for (int i = 0; i < 16; i++){ S += rs1[i]; CC += rc1[i]; }
    unsigned d = CC > 1u ? CC : 1u;
    out[0] = (float)(-S / (double)d);
  }
}

extern "C" void kernel_launch(void* const* d_in, const int* in_sizes, int n_in,
                              void* d_out, int out_size, void* d_ws, size_t ws_size,
                              hipStream_t stream)
{
  const float* logits = (const float*)d_in[0];
  const int*   tgt    = (const int*)d_in[1];
  float* out = (float*)d_out;

  // ws layout: partial sums (hot path) then fallback arrays (cold only)
  double*   p_sle = (double*)d_ws;
  double*   p_sva = p_sle + NSEG;
  unsigned* p_cnt = (unsigned*)(p_sva + NSEG);
  unsigned* keys  = p_cnt + NSEG;            // P_TOT uints (cold path only)
  float*    logp  = (float*)(keys + P_TOT); // P_TOT floats (cold path only)

  hipLaunchKernelGGL(ohem_pass1, dim3(NSEG), dim3(512), 0, stream,
                     logits, tgt, p_sle, p_sva, p_cnt);
  hipLaunchKernelGGL(ohem_finish, dim3(1), dim3(1024), 0, stream,
                     logits, tgt, p_sle, p_sva, p_cnt, keys, logp, out);
}